// Round 1
// baseline (284.342 us; speedup 1.0000x reference)
//
#include <hip/hip_runtime.h>
#include <hip/hip_bf16.h>
#include <stdint.h>

// Problem: 3x Bahdanau attention (p/c/h heads) -> averaged softmax weights -> weighted sum of sentence.
// S=8192, H2=1024, A=2048, E=768. All inputs fp32; output fp32 [1024].
// Strategy: bf16 MFMA for the S x A GEMMs (103 GFLOP dominant cost), fused tanh*v epilogue so
// u[S][A] is never materialized. b_v is softmax-invariant -> dropped. Final pooling GEMV in fp32.

namespace {

constexpr int S = 8192;
constexpr int H = 1024;   // H2
constexpr int A = 2048;
constexpr int E = 768;

typedef __bf16 bf16x8 __attribute__((ext_vector_type(8)));
typedef float f32x4 __attribute__((ext_vector_type(4)));

__device__ __forceinline__ void gl_lds16(const void* g, void* l) {
  __builtin_amdgcn_global_load_lds(
      (const __attribute__((address_space(1))) void*)g,
      (__attribute__((address_space(3))) void*)l, 16, 0, 0);
}

// ---------- P1: sentence fp32 -> bf16 ----------
__global__ void k_cvt_bf16(const float* __restrict__ src, __bf16* __restrict__ dst, int n8) {
  int g = blockIdx.x * blockDim.x + threadIdx.x;
  if (g >= n8) return;
  const float4* s4 = (const float4*)src + (size_t)g * 2;
  float4 a = s4[0], b = s4[1];
  bf16x8 o;
  o[0] = (__bf16)a.x; o[1] = (__bf16)a.y; o[2] = (__bf16)a.z; o[3] = (__bf16)a.w;
  o[4] = (__bf16)b.x; o[5] = (__bf16)b.y; o[6] = (__bf16)b.z; o[7] = (__bf16)b.w;
  *((bf16x8*)dst + g) = o;
}

// ---------- P2: W_sent [H][A] fp32 -> Wt [A][H] bf16 (transpose so B-frags read contiguous k) ----------
__global__ void k_transpose_w(const float* __restrict__ Wp, const float* __restrict__ Wc,
                              const float* __restrict__ Wh, __bf16* __restrict__ Wt) {
  __shared__ float tile[64][65];
  int head = blockIdx.z;
  const float* W = head == 0 ? Wp : (head == 1 ? Wc : Wh);
  __bf16* dst = Wt + (size_t)head * A * H;
  int a0 = blockIdx.x * 64;
  int k0 = blockIdx.y * 64;
  int t = threadIdx.x;
#pragma unroll
  for (int i = 0; i < 16; ++i) {
    int idx = t + i * 256;
    int r = idx >> 6;       // k_local
    int c = idx & 63;       // a_local
    tile[c][r] = W[(size_t)(k0 + r) * A + a0 + c];   // coalesced over c
  }
  __syncthreads();
#pragma unroll
  for (int i = 0; i < 16; ++i) {
    int idx = t + i * 256;
    int al = idx >> 6;
    int kl = idx & 63;
    dst[(size_t)(a0 + al) * H + k0 + kl] = (__bf16)tile[al][kl];  // coalesced over kl
  }
}

// ---------- P3: ctxb[head][a] = b_sent[a] + b_ctx[a] + ctx @ W_ctx ----------
__global__ void k_ctxb(const float* __restrict__ ctx_p, const float* __restrict__ ctx_c,
                       const float* __restrict__ ctx_h,
                       const float* __restrict__ Wc_p, const float* __restrict__ Wc_c,
                       const float* __restrict__ Wc_h,
                       const float* __restrict__ bs_p, const float* __restrict__ bs_c,
                       const float* __restrict__ bs_h,
                       const float* __restrict__ bc_p, const float* __restrict__ bc_c,
                       const float* __restrict__ bc_h,
                       float* __restrict__ ctxb) {
  int head = blockIdx.y;
  const float* ctx = head == 0 ? ctx_p : (head == 1 ? ctx_c : ctx_h);
  const float* Wc  = head == 0 ? Wc_p  : (head == 1 ? Wc_c  : Wc_h);
  const float* bs  = head == 0 ? bs_p  : (head == 1 ? bs_c  : bs_h);
  const float* bc  = head == 0 ? bc_p  : (head == 1 ? bc_c  : bc_h);
  int a = blockIdx.x * 256 + threadIdx.x;
  float s = bs[a] + bc[a];
  for (int e = 0; e < E; ++e) s = fmaf(ctx[e], Wc[(size_t)e * A + a], s);
  ctxb[head * A + a] = s;
}

// ---------- GEMM + fused tanh*v epilogue -> e[head][s] (atomic accumulate over N-tiles) ----------
// m97 structure: 128x128 tile, BK=32, 4 waves 2x2, global_load_lds width 16, mfma 16x16x32 bf16.
__global__ __launch_bounds__(256)
void k_gemm_e(const __bf16* __restrict__ sentB, const __bf16* __restrict__ WtB,
              const float* __restrict__ ctxb,
              const float* __restrict__ v_p, const float* __restrict__ v_c,
              const float* __restrict__ v_h,
              const int* __restrict__ length, float* __restrict__ e_out) {
  int m0 = blockIdx.x * 128;
  int len = length[0];
  if (m0 >= len) return;          // masked rows can never influence the softmax
  int n0 = blockIdx.y * 128;
  int head = blockIdx.z;
  const float* v  = head == 0 ? v_p : (head == 1 ? v_c : v_h);
  const __bf16* Wt = WtB + (size_t)head * A * H;
  const float* cb = ctxb + head * A;
  float* e_h = e_out + head * S;

  __shared__ __align__(16) __bf16 lsA[128 * 32];
  __shared__ __align__(16) __bf16 lsB[128 * 32];
  __shared__ float e_part[128];

  int tid = threadIdx.x;
  if (tid < 128) e_part[tid] = 0.f;

  int lane = tid & 63;
  int wave = tid >> 6;
  int wm = wave >> 1, wn = wave & 1;
  int quad = lane >> 4, l16 = lane & 15;

  f32x4 acc[4][4];
#pragma unroll
  for (int i = 0; i < 4; ++i)
#pragma unroll
    for (int j = 0; j < 4; ++j) acc[i][j] = (f32x4){0.f, 0.f, 0.f, 0.f};

  // staging: thread t loads 16B = 8 bf16; row = t/4, colgroup = t%4; lds offset = t*16B (wave-uniform+lane*16)
  const __bf16* gA0 = sentB + (size_t)(m0 + (tid >> 2)) * H + ((tid & 3) * 8);
  const __bf16* gA1 = gA0 + (size_t)64 * H;
  const __bf16* gB0 = Wt + (size_t)(n0 + (tid >> 2)) * H + ((tid & 3) * 8);
  const __bf16* gB1 = gB0 + (size_t)64 * H;

  for (int k0 = 0; k0 < H; k0 += 32) {
    __syncthreads();                       // protect LDS from overwrite (also covers e_part init)
    gl_lds16(gA0 + k0, lsA + tid * 8);
    gl_lds16(gA1 + k0, lsA + 2048 + tid * 8);
    gl_lds16(gB0 + k0, lsB + tid * 8);
    gl_lds16(gB1 + k0, lsB + 2048 + tid * 8);
    __syncthreads();                       // compiler emits vmcnt(0) drain before barrier

    bf16x8 af[4], bf[4];
#pragma unroll
    for (int i = 0; i < 4; ++i) {
      af[i] = *(const bf16x8*)&lsA[(wm * 64 + i * 16 + l16) * 32 + quad * 8];
      bf[i] = *(const bf16x8*)&lsB[(wn * 64 + i * 16 + l16) * 32 + quad * 8];
    }
#pragma unroll
    for (int i = 0; i < 4; ++i)
#pragma unroll
      for (int j = 0; j < 4; ++j)
        acc[i][j] = __builtin_amdgcn_mfma_f32_16x16x32_bf16(af[i], bf[j], acc[i][j], 0, 0, 0);
  }

  // Epilogue: e[s] += sum_n tanh(u)*v[n].  C/D layout: col = lane&15, row = quad*4 + reg.
  float vj[4], cbj[4];
#pragma unroll
  for (int j = 0; j < 4; ++j) {
    int col = n0 + wn * 64 + j * 16 + l16;
    vj[j] = v[col];
    cbj[j] = cb[col];
  }
#pragma unroll
  for (int i = 0; i < 4; ++i) {
#pragma unroll
    for (int r = 0; r < 4; ++r) {
      float p = 0.f;
#pragma unroll
      for (int j = 0; j < 4; ++j) {
        float u = acc[i][j][r] + cbj[j];
        float ex = __expf(2.f * u);        // tanh = 1 - 2/(e^2x+1); inf-safe at both ends
        float th = 1.f - 2.f / (ex + 1.f);
        p = fmaf(th, vj[j], p);
      }
      p += __shfl_xor(p, 1);
      p += __shfl_xor(p, 2);
      p += __shfl_xor(p, 4);
      p += __shfl_xor(p, 8);               // sum over the 16 cols of this quad-row
      if (l16 == 0) atomicAdd(&e_part[wm * 64 + i * 16 + quad * 4 + r], p);
    }
  }
  __syncthreads();
  if (tid < 128) atomicAdd(&e_h[m0 + tid], e_part[tid]);
}

// ---------- softmax stats per head (max, sum) over s < len ----------
__global__ void k_stats(const float* __restrict__ e_arr, const int* __restrict__ length,
                        float* __restrict__ stats) {
  int head = blockIdx.x;
  const float* e_h = e_arr + head * S;
  int len = min(max(length[0], 0), S);
  int tid = threadIdx.x;
  __shared__ float red[4];
  __shared__ float bmax;

  float m = -3.4e38f;
  for (int s = tid; s < len; s += 256) m = fmaxf(m, e_h[s]);
#pragma unroll
  for (int o = 32; o >= 1; o >>= 1) m = fmaxf(m, __shfl_xor(m, o));
  if ((tid & 63) == 0) red[tid >> 6] = m;
  __syncthreads();
  if (tid == 0) bmax = fmaxf(fmaxf(red[0], red[1]), fmaxf(red[2], red[3]));
  __syncthreads();
  float mm = bmax;

  float ss = 0.f;
  for (int s = tid; s < len; s += 256) ss += __expf(e_h[s] - mm);
#pragma unroll
  for (int o = 32; o >= 1; o >>= 1) ss += __shfl_xor(ss, o);
  __syncthreads();
  if ((tid & 63) == 0) red[tid >> 6] = ss;
  __syncthreads();
  if (tid == 0) {
    stats[head * 2 + 0] = mm;
    stats[head * 2 + 1] = red[0] + red[1] + red[2] + red[3];
  }
}

// ---------- fused[s] = mean of 3 softmax weights (0 beyond len; handles len==0) ----------
__global__ void k_fused(const float* __restrict__ e_arr, const float* __restrict__ stats,
                        const int* __restrict__ length, float* __restrict__ fused) {
  int s = blockIdx.x * 256 + threadIdx.x;
  int len = min(max(length[0], 0), S);
  float f = 0.f;
  if (s < len) {
#pragma unroll
    for (int t = 0; t < 3; ++t)
      f += __expf(e_arr[t * S + s] - stats[t * 2]) / stats[t * 2 + 1];
    f *= (1.f / 3.f);
  }
  fused[s] = f;
}

// ---------- out[h] = sum_s fused[s] * sentence[s][h]  (fp32, memory-bound) ----------
__global__ void k_out(const float* __restrict__ sent, const float* __restrict__ fused,
                      const int* __restrict__ length, float* __restrict__ out) {
  int r0 = blockIdx.x * 128;
  int len = min(max(length[0], 0), S);
  if (r0 >= len) return;
  int col = threadIdx.x * 4;
  int rend = min(r0 + 128, len);
  float4 acc = {0.f, 0.f, 0.f, 0.f};
  for (int r = r0; r < rend; ++r) {
    float w = fused[r];
    float4 x = *(const float4*)(sent + (size_t)r * H + col);
    acc.x = fmaf(w, x.x, acc.x);
    acc.y = fmaf(w, x.y, acc.y);
    acc.z = fmaf(w, x.z, acc.z);
    acc.w = fmaf(w, x.w, acc.w);
  }
  atomicAdd(&out[col + 0], acc.x);
  atomicAdd(&out[col + 1], acc.y);
  atomicAdd(&out[col + 2], acc.z);
  atomicAdd(&out[col + 3], acc.w);
}

}  // namespace

extern "C" void kernel_launch(void* const* d_in, const int* in_sizes, int n_in,
                              void* d_out, int out_size, void* d_ws, size_t ws_size,
                              hipStream_t stream) {
  const float* sentence = (const float*)d_in[0];
  const int* length     = (const int*)d_in[1];
  const float* ctx_p = (const float*)d_in[2];
  const float* ctx_c = (const float*)d_in[3];
  const float* ctx_h = (const float*)d_in[4];
  const float* W_s[3] = {(const float*)d_in[5],  (const float*)d_in[11], (const float*)d_in[17]};
  const float* b_s[3] = {(const float*)d_in[6],  (const float*)d_in[12], (const float*)d_in[18]};
  const float* W_c[3] = {(const float*)d_in[7],  (const float*)d_in[13], (const float*)d_in[19]};
  const float* b_c[3] = {(const float*)d_in[8],  (const float*)d_in[14], (const float*)d_in[20]};
  const float* v_[3]  = {(const float*)d_in[9],  (const float*)d_in[15], (const float*)d_in[21]};
  float* out = (float*)d_out;

  // workspace layout (bytes): total ~28.2 MB
  char* ws = (char*)d_ws;
  __bf16* sentB = (__bf16*)(ws);               // 8192*1024*2   = 16777216
  __bf16* WtB   = (__bf16*)(ws + 16777216);    // 3*2048*1024*2 = 12582912
  float* ctxb   = (float*)(ws + 29360128);     // 3*2048*4      = 24576
  float* e_arr  = (float*)(ws + 29384704);     // 3*8192*4      = 98304
  float* fusedp = (float*)(ws + 29483008);     // 8192*4        = 32768
  float* stats  = (float*)(ws + 29515776);     // 6 floats

  hipMemsetAsync(e_arr, 0, 3 * S * sizeof(float), stream);
  hipMemsetAsync(out, 0, out_size * sizeof(float), stream);

  k_cvt_bf16<<<4096, 256, 0, stream>>>(sentence, sentB, (S * H) / 8);
  k_transpose_w<<<dim3(A / 64, H / 64, 3), 256, 0, stream>>>(W_s[0], W_s[1], W_s[2], WtB);
  k_ctxb<<<dim3(A / 256, 3), 256, 0, stream>>>(ctx_p, ctx_c, ctx_h,
                                               W_c[0], W_c[1], W_c[2],
                                               b_s[0], b_s[1], b_s[2],
                                               b_c[0], b_c[1], b_c[2], ctxb);
  k_gemm_e<<<dim3(S / 128, A / 128, 3), 256, 0, stream>>>(sentB, WtB, ctxb,
                                                          v_[0], v_[1], v_[2], length, e_arr);
  k_stats<<<3, 256, 0, stream>>>(e_arr, length, stats);
  k_fused<<<S / 256, 256, 0, stream>>>(e_arr, stats, length, fusedp);
  k_out<<<S / 128, 256, 0, stream>>>(sentence, fusedp, length, out);
}

// Round 2
// 229.221 us; speedup vs baseline: 1.2405x; 1.2405x over previous
//
#include <hip/hip_runtime.h>
#include <hip/hip_bf16.h>
#include <stdint.h>

// Problem: 3x Bahdanau attention (p/c/h heads) -> averaged softmax weights -> weighted sum of sentence.
// S=8192, H2=1024, A=2048, E=768. All inputs fp32; output fp32 [1024].
// R1: correct, 284us total; GEMM 83us (~37% dense peak = m97 plateau), ~200us in serialized small kernels.
// R2: merge all prep (cvt/transpose/ctxb) into ONE kernel; fuse softmax-weight eval into k_out; 9->6 dispatches.

namespace {

constexpr int S = 8192;
constexpr int H = 1024;   // H2
constexpr int A = 2048;
constexpr int E = 768;

typedef __bf16 bf16x8 __attribute__((ext_vector_type(8)));
typedef float f32x4 __attribute__((ext_vector_type(4)));

__device__ __forceinline__ void gl_lds16(const void* g, void* l) {
  __builtin_amdgcn_global_load_lds(
      (const __attribute__((address_space(1))) void*)g,
      (__attribute__((address_space(3))) void*)l, 16, 0, 0);
}

// ---------- merged prep: [0,4096) cvt sentence->bf16 | [4096,5632) transpose W | [5632,6208) ctxb ----------
// Block ranges branch on blockIdx.x (wave-uniform, no divergence). All three phases are independent,
// so one launch lets them overlap instead of serializing through graph edges.
__global__ __launch_bounds__(256)
void k_prep(const float* __restrict__ sentence, __bf16* __restrict__ sentB,
            const float* __restrict__ Wp, const float* __restrict__ Wc_s,
            const float* __restrict__ Wh, __bf16* __restrict__ WtB,
            const float* __restrict__ ctx_p, const float* __restrict__ ctx_c,
            const float* __restrict__ ctx_h,
            const float* __restrict__ Wcx_p, const float* __restrict__ Wcx_c,
            const float* __restrict__ Wcx_h,
            const float* __restrict__ bs_p, const float* __restrict__ bs_c,
            const float* __restrict__ bs_h,
            const float* __restrict__ bc_p, const float* __restrict__ bc_c,
            const float* __restrict__ bc_h,
            float* __restrict__ ctxb) {
  __shared__ float tile[64][65];
  int b = blockIdx.x;
  int t = threadIdx.x;

  if (b < 4096) {
    // ---- phase 1: sentence fp32 -> bf16, 8 elems/thread ----
    int g = b * 256 + t;
    const float4* s4 = (const float4*)sentence + (size_t)g * 2;
    float4 a = s4[0], c = s4[1];
    bf16x8 o;
    o[0] = (__bf16)a.x; o[1] = (__bf16)a.y; o[2] = (__bf16)a.z; o[3] = (__bf16)a.w;
    o[4] = (__bf16)c.x; o[5] = (__bf16)c.y; o[6] = (__bf16)c.z; o[7] = (__bf16)c.w;
    *((bf16x8*)sentB + g) = o;
  } else if (b < 5632) {
    // ---- phase 2: W_sent [H][A] fp32 -> Wt [A][H] bf16 ----
    int r = b - 4096;                 // 512 tiles per head
    int head = r >> 9; r &= 511;
    const float* W = head == 0 ? Wp : (head == 1 ? Wc_s : Wh);
    __bf16* dst = WtB + (size_t)head * A * H;
    int a0 = (r & 31) * 64;           // 32 a-tiles
    int k0 = (r >> 5) * 64;           // 16 k-tiles
#pragma unroll
    for (int i = 0; i < 16; ++i) {
      int idx = t + i * 256;
      int rr = idx >> 6, cc = idx & 63;
      tile[cc][rr] = W[(size_t)(k0 + rr) * A + a0 + cc];   // coalesced over cc
    }
    __syncthreads();
#pragma unroll
    for (int i = 0; i < 16; ++i) {
      int idx = t + i * 256;
      int al = idx >> 6, kl = idx & 63;
      dst[(size_t)(a0 + al) * H + k0 + kl] = (__bf16)tile[al][kl];  // coalesced over kl
    }
  } else {
    // ---- phase 3: ctxb[head][a] += chunk of ctx @ W_ctx (+bias in chunk 0) ----
    int r = b - 5632;                 // 192 blocks per head: 8 a-blocks x 24 e-chunks
    int head = r / 192; r %= 192;
    int ablk = r & 7;
    int echk = r >> 3;                // 24 chunks of 32
    const float* ctx = head == 0 ? ctx_p : (head == 1 ? ctx_c : ctx_h);
    const float* Wc  = head == 0 ? Wcx_p : (head == 1 ? Wcx_c : Wcx_h);
    int a = ablk * 256 + t;
    float s = 0.f;
    int e0 = echk * 32;
#pragma unroll 8
    for (int e = e0; e < e0 + 32; ++e) s = fmaf(ctx[e], Wc[(size_t)e * A + a], s);
    if (echk == 0) {
      const float* bs = head == 0 ? bs_p : (head == 1 ? bs_c : bs_h);
      const float* bc = head == 0 ? bc_p : (head == 1 ? bc_c : bc_h);
      s += bs[a] + bc[a];
    }
    atomicAdd(&ctxb[head * A + a], s);
  }
}

// ---------- GEMM + fused tanh*v epilogue -> e[head][s] (unchanged from R1: at m97 plateau) ----------
__global__ __launch_bounds__(256)
void k_gemm_e(const __bf16* __restrict__ sentB, const __bf16* __restrict__ WtB,
              const float* __restrict__ ctxb,
              const float* __restrict__ v_p, const float* __restrict__ v_c,
              const float* __restrict__ v_h,
              const int* __restrict__ length, float* __restrict__ e_out) {
  int m0 = blockIdx.x * 128;
  int len = length[0];
  if (m0 >= len) return;          // masked rows can never influence the softmax
  int n0 = blockIdx.y * 128;
  int head = blockIdx.z;
  const float* v  = head == 0 ? v_p : (head == 1 ? v_c : v_h);
  const __bf16* Wt = WtB + (size_t)head * A * H;
  const float* cb = ctxb + head * A;
  float* e_h = e_out + head * S;

  __shared__ __align__(16) __bf16 lsA[128 * 32];
  __shared__ __align__(16) __bf16 lsB[128 * 32];
  __shared__ float e_part[128];

  int tid = threadIdx.x;
  if (tid < 128) e_part[tid] = 0.f;

  int lane = tid & 63;
  int wave = tid >> 6;
  int wm = wave >> 1, wn = wave & 1;
  int quad = lane >> 4, l16 = lane & 15;

  f32x4 acc[4][4];
#pragma unroll
  for (int i = 0; i < 4; ++i)
#pragma unroll
    for (int j = 0; j < 4; ++j) acc[i][j] = (f32x4){0.f, 0.f, 0.f, 0.f};

  const __bf16* gA0 = sentB + (size_t)(m0 + (tid >> 2)) * H + ((tid & 3) * 8);
  const __bf16* gA1 = gA0 + (size_t)64 * H;
  const __bf16* gB0 = Wt + (size_t)(n0 + (tid >> 2)) * H + ((tid & 3) * 8);
  const __bf16* gB1 = gB0 + (size_t)64 * H;

  for (int k0 = 0; k0 < H; k0 += 32) {
    __syncthreads();
    gl_lds16(gA0 + k0, lsA + tid * 8);
    gl_lds16(gA1 + k0, lsA + 2048 + tid * 8);
    gl_lds16(gB0 + k0, lsB + tid * 8);
    gl_lds16(gB1 + k0, lsB + 2048 + tid * 8);
    __syncthreads();

    bf16x8 af[4], bfv[4];
#pragma unroll
    for (int i = 0; i < 4; ++i) {
      af[i]  = *(const bf16x8*)&lsA[(wm * 64 + i * 16 + l16) * 32 + quad * 8];
      bfv[i] = *(const bf16x8*)&lsB[(wn * 64 + i * 16 + l16) * 32 + quad * 8];
    }
#pragma unroll
    for (int i = 0; i < 4; ++i)
#pragma unroll
      for (int j = 0; j < 4; ++j)
        acc[i][j] = __builtin_amdgcn_mfma_f32_16x16x32_bf16(af[i], bfv[j], acc[i][j], 0, 0, 0);
  }

  float vj[4], cbj[4];
#pragma unroll
  for (int j = 0; j < 4; ++j) {
    int col = n0 + wn * 64 + j * 16 + l16;
    vj[j] = v[col];
    cbj[j] = cb[col];
  }
#pragma unroll
  for (int i = 0; i < 4; ++i) {
#pragma unroll
    for (int r = 0; r < 4; ++r) {
      float p = 0.f;
#pragma unroll
      for (int j = 0; j < 4; ++j) {
        float u = acc[i][j][r] + cbj[j];
        float ex = __expf(2.f * u);        // tanh = 1 - 2/(e^2x+1); inf-safe at both ends
        float th = 1.f - 2.f / (ex + 1.f);
        p = fmaf(th, vj[j], p);
      }
      p += __shfl_xor(p, 1);
      p += __shfl_xor(p, 2);
      p += __shfl_xor(p, 4);
      p += __shfl_xor(p, 8);
      if (l16 == 0) atomicAdd(&e_part[wm * 64 + i * 16 + quad * 4 + r], p);
    }
  }
  __syncthreads();
  if (tid < 128) atomicAdd(&e_h[m0 + tid], e_part[tid]);
}

// ---------- softmax stats per head (max, sum) over s < len ----------
__global__ void k_stats(const float* __restrict__ e_arr, const int* __restrict__ length,
                        float* __restrict__ stats) {
  int head = blockIdx.x;
  const float* e_h = e_arr + head * S;
  int len = min(max(length[0], 0), S);
  int tid = threadIdx.x;
  __shared__ float red[4];
  __shared__ float bmax;

  float m = -3.4e38f;
  for (int s = tid; s < len; s += 256) m = fmaxf(m, e_h[s]);
#pragma unroll
  for (int o = 32; o >= 1; o >>= 1) m = fmaxf(m, __shfl_xor(m, o));
  if ((tid & 63) == 0) red[tid >> 6] = m;
  __syncthreads();
  if (tid == 0) bmax = fmaxf(fmaxf(red[0], red[1]), fmaxf(red[2], red[3]));
  __syncthreads();
  float mm = bmax;

  float ss = 0.f;
  for (int s = tid; s < len; s += 256) ss += __expf(e_h[s] - mm);
#pragma unroll
  for (int o = 32; o >= 1; o >>= 1) ss += __shfl_xor(ss, o);
  __syncthreads();
  if ((tid & 63) == 0) red[tid >> 6] = ss;
  __syncthreads();
  if (tid == 0) {
    stats[head * 2 + 0] = mm;
    stats[head * 2 + 1] = red[0] + red[1] + red[2] + red[3];
  }
}

// ---------- out[h] = sum_s w(s) * sentence[s][h], w computed inline from e+stats ----------
// 256 blocks x 32 rows each (4x more parallelism than R1), k_fused pass eliminated.
__global__ void k_out(const float* __restrict__ sent, const float* __restrict__ e_arr,
                      const float* __restrict__ stats, const int* __restrict__ length,
                      float* __restrict__ out) {
  int len = min(max(length[0], 0), S);
  int r0 = blockIdx.x * 32;
  if (r0 >= len) return;
  int col = threadIdx.x * 4;
  int rend = min(r0 + 32, len);
  float m0 = stats[0], s0 = stats[1];
  float m1 = stats[2], s1 = stats[3];
  float m2 = stats[4], s2 = stats[5];
  float4 acc = {0.f, 0.f, 0.f, 0.f};
  for (int r = r0; r < rend; ++r) {
    float w = (__expf(e_arr[r] - m0) / s0 +
               __expf(e_arr[S + r] - m1) / s1 +
               __expf(e_arr[2 * S + r] - m2) / s2) * (1.f / 3.f);
    float4 x = *(const float4*)(sent + (size_t)r * H + col);
    acc.x = fmaf(w, x.x, acc.x);
    acc.y = fmaf(w, x.y, acc.y);
    acc.z = fmaf(w, x.z, acc.z);
    acc.w = fmaf(w, x.w, acc.w);
  }
  atomicAdd(&out[col + 0], acc.x);
  atomicAdd(&out[col + 1], acc.y);
  atomicAdd(&out[col + 2], acc.z);
  atomicAdd(&out[col + 3], acc.w);
}

}  // namespace

extern "C" void kernel_launch(void* const* d_in, const int* in_sizes, int n_in,
                              void* d_out, int out_size, void* d_ws, size_t ws_size,
                              hipStream_t stream) {
  const float* sentence = (const float*)d_in[0];
  const int* length     = (const int*)d_in[1];
  const float* ctx_p = (const float*)d_in[2];
  const float* ctx_c = (const float*)d_in[3];
  const float* ctx_h = (const float*)d_in[4];
  const float* W_s[3] = {(const float*)d_in[5],  (const float*)d_in[11], (const float*)d_in[17]};
  const float* b_s[3] = {(const float*)d_in[6],  (const float*)d_in[12], (const float*)d_in[18]};
  const float* W_c[3] = {(const float*)d_in[7],  (const float*)d_in[13], (const float*)d_in[19]};
  const float* b_c[3] = {(const float*)d_in[8],  (const float*)d_in[14], (const float*)d_in[20]};
  const float* v_[3]  = {(const float*)d_in[9],  (const float*)d_in[15], (const float*)d_in[21]};
  float* out = (float*)d_out;

  // workspace layout (bytes)
  char* ws = (char*)d_ws;
  __bf16* sentB = (__bf16*)(ws);               // 8192*1024*2   = 16777216
  __bf16* WtB   = (__bf16*)(ws + 16777216);    // 3*2048*1024*2 = 12582912
  float* ctxb   = (float*)(ws + 29360128);     // 3*2048*4      = 24576
  float* e_arr  = (float*)(ws + 29384704);     // 3*8192*4      = 98304
  float* stats  = (float*)(ws + 29483008);     // 6 floats

  // one memset covers ctxb (needs 0 for atomic accumulate) + e_arr (same)
  hipMemsetAsync(ctxb, 0, (A * 3 + S * 3) * sizeof(float), stream);
  hipMemsetAsync(out, 0, out_size * sizeof(float), stream);

  k_prep<<<6208, 256, 0, stream>>>(sentence, sentB,
                                   W_s[0], W_s[1], W_s[2], WtB,
                                   ctx_p, ctx_c, ctx_h,
                                   W_c[0], W_c[1], W_c[2],
                                   b_s[0], b_s[1], b_s[2],
                                   b_c[0], b_c[1], b_c[2], ctxb);
  k_gemm_e<<<dim3(S / 128, A / 128, 3), 256, 0, stream>>>(sentB, WtB, ctxb,
                                                          v_[0], v_[1], v_[2], length, e_arr);
  k_stats<<<3, 256, 0, stream>>>(e_arr, length, stats);
  k_out<<<S / 32, 256, 0, stream>>>(sentence, e_arr, stats, length, out);
}